// Round 4
// baseline (13926.022 us; speedup 1.0000x reference)
//
#include <hip/hip_runtime.h>
#include <math.h>

// NeuralODE: sequential RK4 orbit propagation with J2-J5 gravity + tiny MLP
// correction. Latency-bound: single wave (64 lanes), whole time loop in-kernel.
//
// R4 structure:
//  * Gravity is software-pipelined ONE RK4 STAGE AHEAD: stage s+1 positions
//    depend only on accel s-1, so gravity(pos_{s+1}) issues before mlp(state_s)
//    and fills the MLP's latency bubbles.
//  * Neuron->lane map: nrn = (tid&15) + 16*(tid>>5); ctx = (tid>>4)&1.
//    Rows (16-lane groups) 0,2 are ctx A; rows 1,3 are ctx B. Each neuron
//    appears once per ctx. L3 reduction = 4x DPP row_ror adds (16-row sums)
//    + permlane32_swap self-sum (adds lane^32's row sum -> full 32-neuron sum)
//    -- both primitives verified in R3. Dual-weight (wA/wB) + cndmask gives
//    orientation-proof uniform ax, ay; az chain is uniform by construction.
//  * gx = px*Gxy, gy = py*Gxy with one shared polynomial Gxy.
//  * h1 broadcast via 32x v_readlane into SGPRs (no LDS).

namespace {
constexpr double dMU = 398600.4418;
constexpr double dRE = 6378.137;
constexpr double dJ2 = 0.00108262668;
constexpr double dJ3 = -2.53265648e-06;
constexpr double dJ4 = -1.61962159e-06;
constexpr double dJ5 = -2.27296082e-07;

constexpr float MU_F = (float)dMU;
constexpr float C2_F = (float)(-1.5 * dJ2 * dMU * dRE * dRE);
constexpr float C3_F = (float)(-2.5 * dJ3 * dMU * dRE * dRE * dRE);
constexpr float C4_F = (float)(15.0 / 8.0 * dJ4 * dMU * dRE * dRE * dRE * dRE);
constexpr float C5_F = (float)(3.0 / 8.0 * dJ5 * dMU * dRE * dRE * dRE * dRE * dRE);
constexpr float D5_F = (float)(-(15.0 / 8.0) * dJ5 * dMU * dRE * dRE * dRE * dRE * dRE);
constexpr float IRREF = (float)(1.0 / 7000.0);
constexpr float IVREF = (float)(1.0 / 7.5);
constexpr float AREF  = (float)(7.5 * 7.5 / 7000.0);
} // namespace

__device__ __forceinline__ float fast_tanh(float x) {
    // tanh(x) = 1 - 2/(exp(2x)+1); exp(2x) = exp2(2*log2(e)*x)
    float e = __builtin_amdgcn_exp2f(x * 2.8853900817779268f);
    return 1.0f - 2.0f * __builtin_amdgcn_rcpf(e + 1.0f);
}

// x += rotate_within_16row(x) ; CTRL = 0x120+N (row_ror:N)
template <int CTRL>
__device__ __forceinline__ float dpp_ror_add(float x) {
    int p = __builtin_amdgcn_update_dpp(0, __float_as_int(x), CTRL, 0xf, 0xf, true);
    return x + __int_as_float(p);
}

// 4 ror-adds -> every lane holds its 16-row sum; permlane32_swap self-sum
// adds rowsum(lane^32). Result[lane] = rowsum(lane) + rowsum(lane^32).
// (Verified primitive pair from R3.)
__device__ __forceinline__ float reduce_rows_swap(float p) {
    p = dpp_ror_add<0x121>(p);  // row_ror:1
    p = dpp_ror_add<0x122>(p);  // row_ror:2
    p = dpp_ror_add<0x124>(p);  // row_ror:4
    p = dpp_ror_add<0x128>(p);  // row_ror:8
    int a = __float_as_int(p), b = __float_as_int(p);
    asm("s_nop 0\n\tv_permlane32_swap_b32 %0, %1\n\ts_nop 0"
        : "+v"(a), "+v"(b));
    return __int_as_float(a) + __int_as_float(b);
}

__global__ void __launch_bounds__(64, 1)
node_kernel(const float* __restrict__ state0,
            const float* __restrict__ W1, const float* __restrict__ b1,
            const float* __restrict__ W2, const float* __restrict__ b2,
            const float* __restrict__ W3, const float* __restrict__ b3,
            const float* __restrict__ plog_scale,
            const int*  __restrict__ pdt,
            float* __restrict__ out, int M)
{
    const int tid = (int)threadIdx.x;
    const int nrn = (tid & 15) + ((tid >> 5) << 4);  // rows {0,2}: ctx A
    const bool ctxA = ((tid >> 4) & 1) == 0;

    // dt arrives as a 1-element array; sniff int32 vs float32 bit pattern.
    int db = *pdt;
    float dtf = (db >= 1 && db <= 1000000) ? (float)db : __int_as_float(db);
    const float hd  = 0.5f * dtf;
    const float dt6 = dtf * (1.0f / 6.0f);

    const float scale =
        __builtin_amdgcn_exp2f(plog_scale[0] * 1.4426950408889634f) * AREF;
    const float sb0 = scale * b3[0], sb1 = scale * b3[1], sb2 = scale * b3[2];

    // Per-lane weights; fold 1/R_REF, 1/V_REF into W1 rows.
    float w1r[6];
    #pragma unroll
    for (int k = 0; k < 3; ++k) w1r[k] = W1[nrn * 6 + k] * IRREF;
    #pragma unroll
    for (int k = 3; k < 6; ++k) w1r[k] = W1[nrn * 6 + k] * IVREF;
    const float b1r = b1[nrn];
    float w2r[32];
    #pragma unroll
    for (int i = 0; i < 32; ++i) w2r[i] = W2[nrn * 32 + i];
    const float b2r = b2[nrn];
    // Dual L3 weights: ctx-A lanes carry (W3row0, W3row1), ctx-B the reverse.
    const float wA = ctxA ? W3[nrn] : W3[32 + nrn];
    const float wB = ctxA ? W3[32 + nrn] : W3[nrn];
    const float wz = W3[64 + nrn];

    float px = state0[0], py = state0[1], pz = state0[2];
    float vx = state0[3], vy = state0[4], vz = state0[5];

    // gravity(pos) -> (gx,gy,gz); shared polynomial for x/y.
    auto gravity = [&](float Px, float Py, float Pz,
                       float& gx, float& gy, float& gz) {
        float r2  = fmaf(Px, Px, fmaf(Py, Py, Pz * Pz));
        float ir  = __builtin_amdgcn_rsqf(r2);
        float ir2 = ir * ir;
        float ir3 = ir2 * ir;
        float ir5 = ir3 * ir2;
        float ir7 = ir5 * ir2;
        float ir9 = ir7 * ir2;
        float z2  = Pz * Pz;
        float zr2 = z2 * ir2;
        float zr4 = zr2 * zr2;

        float gmr3 = -MU_F * ir3;
        float c2 = C2_F * ir5;
        float c3 = C3_F * ir7;
        float c4 = C4_F * ir7;
        float c5 = C5_F * ir9;
        float c5z = c5 * Pz;

        float q2 = fmaf(-5.0f, zr2, 1.0f);
        float t3 = Pz * fmaf(-7.0f, zr2, 3.0f);
        float p4 = fmaf(21.0f, zr4, fmaf(-14.0f, zr2, 1.0f));
        float p5 = fmaf(231.0f, zr4, fmaf(-210.0f, zr2, 35.0f));

        // Gxy = gmr3 + c2*q2 + c3*t3 + c4*p4 + c5z*p5
        float Gxy = fmaf(c2, q2, gmr3);
        Gxy = fmaf(c3, t3, Gxy);
        Gxy = fmaf(c4, p4, Gxy);
        Gxy = fmaf(c5z, p5, Gxy);
        gx = Px * Gxy;
        gy = Py * Gxy;

        float gzv = gmr3 * Pz;
        gzv = fmaf(c2 * Pz, fmaf(-5.0f, zr2, 3.0f), gzv);
        gzv = fmaf(c3, fmaf(z2, fmaf(-7.0f, zr2, 6.0f), -0.6f * r2), gzv);
        gzv = fmaf(c4 * Pz, fmaf(21.0f, zr4, fmaf(-23.333333333333332f, zr2, 5.0f)), gzv);
        gzv = fmaf(c5 * z2, fmaf(231.0f, zr4, fmaf(-315.0f, zr2, 105.0f)), gzv);
        gz = fmaf(D5_F, ir7, gzv);
    };

    // mlp(state) -> scaled correction (uniform across lanes).
    auto mlp = [&](float Px, float Py, float Pz, float Vx, float Vy, float Vz,
                   float& cx, float& cy, float& cz) {
        float pre = b1r;
        pre = fmaf(w1r[0], Px, pre);
        pre = fmaf(w1r[1], Py, pre);
        pre = fmaf(w1r[2], Pz, pre);
        pre = fmaf(w1r[3], Vx, pre);
        pre = fmaf(w1r[4], Vy, pre);
        pre = fmaf(w1r[5], Vz, pre);
        float h1 = fast_tanh(pre);

        // Broadcast: neuron i's h1 lives at lane i (i<16) or lane i+16 (i>=16).
        float hs[32];
        #pragma unroll
        for (int i = 0; i < 32; ++i) {
            const int ln = (i < 16) ? i : (i + 16);
            hs[i] = __int_as_float(__builtin_amdgcn_readlane(__float_as_int(h1), ln));
        }

        float a0 = b2r, a1 = 0.0f, a2 = 0.0f, a3 = 0.0f;
        #pragma unroll
        for (int i = 0; i < 8; ++i) {
            a0 = fmaf(w2r[4 * i + 0], hs[4 * i + 0], a0);
            a1 = fmaf(w2r[4 * i + 1], hs[4 * i + 1], a1);
            a2 = fmaf(w2r[4 * i + 2], hs[4 * i + 2], a2);
            a3 = fmaf(w2r[4 * i + 3], hs[4 * i + 3], a3);
        }
        float h2 = fast_tanh((a0 + a1) + (a2 + a3));

        // L3: dual-weight reductions; qA = {A on ctx-A rows, B on ctx-B rows},
        // qB = the reverse; az chain is uniform directly.
        float qA = reduce_rows_swap(wA * h2);
        float qB = reduce_rows_swap(wB * h2);
        float s2 = reduce_rows_swap(wz * h2);
        float s0 = ctxA ? qA : qB;   // ax partial-sum, uniform
        float s1 = ctxA ? qB : qA;   // ay partial-sum, uniform
        cx = fmaf(scale, s0, sb0);
        cy = fmaf(scale, s1, sb1);
        cz = fmaf(scale, s2, sb2);
    };

    // Prologue: gravity for stage 1 of the first step.
    float g1x, g1y, g1z;
    gravity(px, py, pz, g1x, g1y, g1z);

    for (int m = 0; m < M; ++m) {
        // ---- stage 1 (state: px,vx; gravity g1 in hand) ----
        float p2x = fmaf(hd, vx, px), p2y = fmaf(hd, vy, py), p2z = fmaf(hd, vz, pz);
        float g2x, g2y, g2z;
        gravity(p2x, p2y, p2z, g2x, g2y, g2z);          // overlaps mlp1
        float c1x, c1y, c1z;
        mlp(px, py, pz, vx, vy, vz, c1x, c1y, c1z);
        float a1x = g1x + c1x, a1y = g1y + c1y, a1z = g1z + c1z;

        // ---- stage 2 ----
        float v2x = fmaf(hd, a1x, vx), v2y = fmaf(hd, a1y, vy), v2z = fmaf(hd, a1z, vz);
        float p3x = fmaf(hd, v2x, px), p3y = fmaf(hd, v2y, py), p3z = fmaf(hd, v2z, pz);
        float g3x, g3y, g3z;
        gravity(p3x, p3y, p3z, g3x, g3y, g3z);          // overlaps mlp2
        float c2x, c2y, c2z;
        mlp(p2x, p2y, p2z, v2x, v2y, v2z, c2x, c2y, c2z);
        float a2x = g2x + c2x, a2y = g2y + c2y, a2z = g2z + c2z;

        // ---- stage 3 ----
        float v3x = fmaf(hd, a2x, vx), v3y = fmaf(hd, a2y, vy), v3z = fmaf(hd, a2z, vz);
        float p4x = fmaf(dtf, v3x, px), p4y = fmaf(dtf, v3y, py), p4z = fmaf(dtf, v3z, pz);
        float g4x, g4y, g4z;
        gravity(p4x, p4y, p4z, g4x, g4y, g4z);          // overlaps mlp3
        float c3x, c3y, c3z;
        mlp(p3x, p3y, p3z, v3x, v3y, v3z, c3x, c3y, c3z);
        float a3x = g3x + c3x, a3y = g3y + c3y, a3z = g3z + c3z;

        // ---- stage 4 ----
        float v4x = fmaf(dtf, a3x, vx), v4y = fmaf(dtf, a3y, vy), v4z = fmaf(dtf, a3z, vz);
        // Next-step positions (k_i position-parts are the stage velocities).
        float pxn = fmaf(dt6, (vx + 2.0f * (v2x + v3x)) + v4x, px);
        float pyn = fmaf(dt6, (vy + 2.0f * (v2y + v3y)) + v4y, py);
        float pzn = fmaf(dt6, (vz + 2.0f * (v2z + v3z)) + v4z, pz);
        gravity(pxn, pyn, pzn, g1x, g1y, g1z);          // next-iter g1, overlaps mlp4
        float c4x, c4y, c4z;
        mlp(p4x, p4y, p4z, v4x, v4y, v4z, c4x, c4y, c4z);
        float a4x = g4x + c4x, a4y = g4y + c4y, a4z = g4z + c4z;

        float vxn = fmaf(dt6, (a1x + 2.0f * (a2x + a3x)) + a4x, vx);
        float vyn = fmaf(dt6, (a1y + 2.0f * (a2y + a3y)) + a4y, vy);
        float vzn = fmaf(dt6, (a1z + 2.0f * (a2z + a3z)) + a4z, vz);

        px = pxn; py = pyn; pz = pzn;
        vx = vxn; vy = vyn; vz = vzn;

        if (tid == 0) {
            float2* o = (float2*)(out + (size_t)m * 6);
            o[0] = make_float2(px, py);
            o[1] = make_float2(pz, vx);
            o[2] = make_float2(vy, vz);
        }
    }
}

extern "C" void kernel_launch(void* const* d_in, const int* in_sizes, int n_in,
                              void* d_out, int out_size, void* d_ws, size_t ws_size,
                              hipStream_t stream) {
    const float* state0 = (const float*)d_in[0];
    // d_in[1] = eval_times (only its length matters)
    const float* W1 = (const float*)d_in[2];
    const float* b1 = (const float*)d_in[3];
    const float* W2 = (const float*)d_in[4];
    const float* b2 = (const float*)d_in[5];
    const float* W3 = (const float*)d_in[6];
    const float* b3 = (const float*)d_in[7];
    const float* ls = (const float*)d_in[8];
    // d_in[9] = t0 (unused)
    const int* pdt  = (const int*)d_in[10];
    const int M = in_sizes[1];

    node_kernel<<<dim3(1), dim3(64), 0, stream>>>(
        state0, W1, b1, W2, b2, W3, b3, ls, pdt, (float*)d_out, M);
}

// Round 5
// 10463.262 us; speedup vs baseline: 1.3309x; 1.3309x over previous
//
#include <hip/hip_runtime.h>
#include <math.h>

// NeuralODE: sequential RK4 orbit propagation, J2-J5 gravity + tiny MLP.
// Latency/issue-bound: single wave; model = 1 instr per 4cy wave cadence,
// so R5 minimizes ISSUED OPS (~157 -> ~115 per dynamics eval).
//
// Lane map: out-neuron o = (tid&15)+16*bit4(tid); input-half ibase = 16*bit5(tid).
//  rows(16-lane): row0:(o 0-15, in 0-15) row1:(o 16-31, in 0-15)
//                 row2:(o 0-15, in 16-31) row3:(o 16-31, in 16-31)
//  L1: lane computes h1[own input neuron] (pre delivered via prefolded bases).
//  L2: 16 DPP row_ror reads of h1 (self-calibrated weight order) -> half-dot;
//      permlane32_swap self-SUM (lane^32 = same o, other input half) -> pre2.
//  L3: w3*h2, 4x ror-add rowsum; dot = readlane(row0)+readlane(row1).
//  All stage handoffs: pre_{s+1} = PPfull_{s+1} + dot(wc, s-vec) (3 fma);
//  gravity/positions/velocity bookkeeping fully prefolded off the handoff.

namespace {
constexpr double dMU = 398600.4418;
constexpr double dRE = 6378.137;
constexpr double dJ2 = 0.00108262668;
constexpr double dJ3 = -2.53265648e-06;
constexpr double dJ4 = -1.61962159e-06;
constexpr double dJ5 = -2.27296082e-07;

constexpr float MU_F = (float)dMU;
constexpr float C2_F = (float)(-1.5 * dJ2 * dMU * dRE * dRE);
constexpr float C3_F = (float)(-2.5 * dJ3 * dMU * dRE * dRE * dRE);
constexpr float C4_F = (float)(15.0 / 8.0 * dJ4 * dMU * dRE * dRE * dRE * dRE);
constexpr float C5_F = (float)(3.0 / 8.0 * dJ5 * dMU * dRE * dRE * dRE * dRE * dRE);
constexpr float D5_F = (float)(-(15.0 / 8.0) * dJ5 * dMU * dRE * dRE * dRE * dRE * dRE);
constexpr float IRREF = (float)(1.0 / 7000.0);
constexpr float IVREF = (float)(1.0 / 7.5);
constexpr float AREF  = (float)(7.5 * 7.5 / 7000.0);
constexpr float L2E2  = 2.8853900817779268f;  // 2*log2(e)
} // namespace

typedef float f2 __attribute__((ext_vector_type(2)));
__device__ __forceinline__ f2 f2s(float s) { return (f2){s, s}; }
__device__ __forceinline__ f2 fma2(f2 a, f2 b, f2 c) {
    return __builtin_elementwise_fma(a, b, c);
}

template <int CTRL>
__device__ __forceinline__ float rotf(float x) {
    return __int_as_float(
        __builtin_amdgcn_update_dpp(0, __float_as_int(x), CTRL, 0xf, 0xf, true));
}
template <int CTRL>
__device__ __forceinline__ int roti(int x) {
    return __builtin_amdgcn_update_dpp(0, x, CTRL, 0xf, 0xf, true);
}
// a+b = x[l] + x[l^32]  (verified R3 primitive; orientation-proof sum)
__device__ __forceinline__ float swap32sum(float x) {
    int a = __float_as_int(x), b = __float_as_int(x);
    asm("s_nop 0\n\tv_permlane32_swap_b32 %0, %1\n\ts_nop 0"
        : "+v"(a), "+v"(b));
    return __int_as_float(a) + __int_as_float(b);
}
__device__ __forceinline__ float rdl(float x, int lane) {
    return __int_as_float(__builtin_amdgcn_readlane(__float_as_int(x), lane));
}
// input already scaled by 2*log2e: tanh = 1 - 2/(2^sp + 1)
__device__ __forceinline__ float tanhx(float sp) {
    float e = __builtin_amdgcn_exp2f(sp);
    return fmaf(-2.0f, __builtin_amdgcn_rcpf(e + 1.0f), 1.0f);
}

struct G3 { f2 xy; float z; };

__device__ __forceinline__ G3 gravity(f2 pxy, float pz) {
    float zz = pz * pz;
    float r2 = fmaf(pxy.x, pxy.x, fmaf(pxy.y, pxy.y, zz));
    float ir = __builtin_amdgcn_rsqf(r2);
    float ir2 = ir * ir, ir3 = ir2 * ir;
    float s  = zz * ir2;
    float s2 = s * s;
    // packed polynomial pairs {xy-form, z-form}
    f2 qp  = fma2(f2s(-5.0f), f2s(s), (f2){1.0f, 3.0f});
    f2 p4p = fma2(f2s(21.0f), f2s(s2),
                  fma2((f2){-14.0f, -70.0f / 3.0f}, f2s(s), (f2){1.0f, 5.0f}));
    f2 p5p = fma2(f2s(231.0f), f2s(s2),
                  fma2((f2){-210.0f, -315.0f}, f2s(s), (f2){35.0f, 105.0f}));
    f2 t3p = fma2(f2s(-7.0f), f2s(s), (f2){3.0f, 6.0f});
    float t3  = pz * t3p.x;
    float p3z = fmaf(s, t3p.y, -0.6f);
    float t5  = pz * p5p.x;
    // Horner pair in ir2: H.x -> Gxy, H.y -> z-multiplied part of gz
    f2 H = (f2){fmaf(C3_F, t3, C4_F * p4p.x), C4_F * p4p.y};
    H = fma2(f2s(ir2), (f2){C5_F * t5, 0.0f}, H);   // wait: order fixed below
    // NOTE: the line above must be the INNERMOST term; rebuild properly:
    // (kept explicit for clarity)
    f2 inner = (f2){fmaf(C3_F, t3, C4_F * p4p.x), C4_F * p4p.y};
    H = fma2(f2s(ir2), (f2){C5_F * t5, 0.0f}, inner);
    H = fma2(f2s(ir2), H, f2s(C2_F) * qp);
    H = fma2(f2s(ir2), H, f2s(-MU_F));
    float Gxy = ir3 * H.x;
    float gzA = (pz * ir3) * H.y;
    float ir5 = ir3 * ir2;
    float w = fmaf(C5_F, s * p5p.y, D5_F);
    w = fmaf(ir2, w, C3_F * p3z);
    G3 g;
    g.xy = pxy * f2s(Gxy);
    g.z  = fmaf(ir5, w, gzA);
    return g;
}

__global__ void __launch_bounds__(64, 1)
node_kernel(const float* __restrict__ state0,
            const float* __restrict__ W1, const float* __restrict__ b1,
            const float* __restrict__ W2, const float* __restrict__ b2,
            const float* __restrict__ W3, const float* __restrict__ b3,
            const float* __restrict__ plog_scale,
            const int*  __restrict__ pdt,
            float* __restrict__ out, int M)
{
    const int tid  = (int)threadIdx.x;
    const int lid  = tid & 15;
    const int o    = lid + (((tid >> 4) & 1) << 4);  // output neuron
    const int ibase = ((tid >> 5) & 1) << 4;          // input half base
    const int nin  = lid + ibase;                     // input neuron (L1)

    // dt arrives as a 1-element array; sniff int32 vs float32 bit pattern.
    int db = *pdt;
    float dtf = (db >= 1 && db <= 1000000) ? (float)db : __int_as_float(db);
    const float hd   = 0.5f * dtf;
    const float dt6  = dtf * (1.0f / 6.0f);
    const float hd2  = hd * hd;
    const float dthd = dtf * hd;
    const float dt26 = dtf * dtf * (1.0f / 6.0f);

    const float scale =
        __builtin_amdgcn_exp2f(plog_scale[0] * 1.4426950408889634f) * AREF;
    const f2   sbxy = (f2){scale * b3[0], scale * b3[1]};
    const float sbz = scale * b3[2];

    // ---- per-lane weights (pre-scaled by 2*log2e where they feed a tanh) ----
    const float w1p0 = W1[nin * 6 + 0] * (L2E2 * IRREF);
    const float w1p1 = W1[nin * 6 + 1] * (L2E2 * IRREF);
    const float w1p2 = W1[nin * 6 + 2] * (L2E2 * IRREF);
    const float w1v0 = W1[nin * 6 + 3] * (L2E2 * IVREF);
    const float w1v1 = W1[nin * 6 + 4] * (L2E2 * IVREF);
    const float w1v2 = W1[nin * 6 + 5] * (L2E2 * IVREF);
    const float b1r  = b1[nin] * L2E2;

    // self-calibrated DPP rotation source map (within-row lane index)
    int ns1  = roti<0x121>(lid), ns2  = roti<0x122>(lid), ns3  = roti<0x123>(lid);
    int ns4  = roti<0x124>(lid), ns5  = roti<0x125>(lid), ns6  = roti<0x126>(lid);
    int ns7  = roti<0x127>(lid), ns8  = roti<0x128>(lid), ns9  = roti<0x129>(lid);
    int ns10 = roti<0x12A>(lid), ns11 = roti<0x12B>(lid), ns12 = roti<0x12C>(lid);
    int ns13 = roti<0x12D>(lid), ns14 = roti<0x12E>(lid), ns15 = roti<0x12F>(lid);
    const float* W2r = W2 + o * 32 + ibase;
    float w2r[16];
    w2r[0]  = W2r[lid]  * L2E2;
    w2r[1]  = W2r[ns1]  * L2E2;  w2r[2]  = W2r[ns2]  * L2E2;
    w2r[3]  = W2r[ns3]  * L2E2;  w2r[4]  = W2r[ns4]  * L2E2;
    w2r[5]  = W2r[ns5]  * L2E2;  w2r[6]  = W2r[ns6]  * L2E2;
    w2r[7]  = W2r[ns7]  * L2E2;  w2r[8]  = W2r[ns8]  * L2E2;
    w2r[9]  = W2r[ns9]  * L2E2;  w2r[10] = W2r[ns10] * L2E2;
    w2r[11] = W2r[ns11] * L2E2;  w2r[12] = W2r[ns12] * L2E2;
    w2r[13] = W2r[ns13] * L2E2;  w2r[14] = W2r[ns14] * L2E2;
    w2r[15] = W2r[ns15] * L2E2;
    const float b2h = b2[o] * (0.5f * L2E2);  // halved: swap32 sum doubles it
    const float w3x = W3[o], w3y = W3[32 + o], w3z = W3[64 + o];

    // chain-out weight vectors (scale premultiplied)
    const float wcH0 = (scale * hd)  * w1v0, wcH1 = (scale * hd)  * w1v1,
                wcH2 = (scale * hd)  * w1v2;
    const float wcD0 = (scale * dtf) * w1v0, wcD1 = (scale * dtf) * w1v1,
                wcD2 = (scale * dtf) * w1v2;
    const float wc60 = (scale * dt6) * w1v0, wc61 = (scale * dt6) * w1v1,
                wc62 = (scale * dt6) * w1v2;

    auto dotP = [&](f2 xy, float z) {
        return fmaf(w1p2, z, fmaf(w1p1, xy.y, w1p0 * xy.x));
    };
    auto dotV = [&](f2 xy, float z) {
        return fmaf(w1v2, z, fmaf(w1v1, xy.y, w1v0 * xy.x));
    };

    // MLP chain: pre(scaled) -> uniform (s0,s1,s2) = W3 . tanh(W2 tanh-layer)
    auto mlpchain = [&](float pre, float& s0, float& s1, float& s2) {
        float h1 = tanhx(pre);
        float a0 = fmaf(h1, w2r[0], b2h);
        float a1 = rotf<0x121>(h1) * w2r[1];
        float a2 = rotf<0x122>(h1) * w2r[2];
        float a3 = rotf<0x123>(h1) * w2r[3];
        a0 = fmaf(rotf<0x124>(h1), w2r[4],  a0);
        a1 = fmaf(rotf<0x125>(h1), w2r[5],  a1);
        a2 = fmaf(rotf<0x126>(h1), w2r[6],  a2);
        a3 = fmaf(rotf<0x127>(h1), w2r[7],  a3);
        a0 = fmaf(rotf<0x128>(h1), w2r[8],  a0);
        a1 = fmaf(rotf<0x129>(h1), w2r[9],  a1);
        a2 = fmaf(rotf<0x12A>(h1), w2r[10], a2);
        a3 = fmaf(rotf<0x12B>(h1), w2r[11], a3);
        a0 = fmaf(rotf<0x12C>(h1), w2r[12], a0);
        a1 = fmaf(rotf<0x12D>(h1), w2r[13], a1);
        a2 = fmaf(rotf<0x12E>(h1), w2r[14], a2);
        a3 = fmaf(rotf<0x12F>(h1), w2r[15], a3);
        float accA = (a0 + a2) + (a1 + a3);
        float pre2 = swap32sum(accA);       // + other input half (+b2)
        float h2 = tanhx(pre2);
        float r0 = w3x * h2, r1 = w3y * h2, r2 = w3z * h2;
        r0 += rotf<0x121>(r0); r1 += rotf<0x121>(r1); r2 += rotf<0x121>(r2);
        r0 += rotf<0x122>(r0); r1 += rotf<0x122>(r1); r2 += rotf<0x122>(r2);
        r0 += rotf<0x124>(r0); r1 += rotf<0x124>(r1); r2 += rotf<0x124>(r2);
        r0 += rotf<0x128>(r0); r1 += rotf<0x128>(r1); r2 += rotf<0x128>(r2);
        s0 = rdl(r0, 0) + rdl(r0, 16);      // row0 (o<16) + row1 (o>=16)
        s1 = rdl(r1, 0) + rdl(r1, 16);
        s2 = rdl(r2, 0) + rdl(r2, 16);
    };

    // ---- prologue ----
    f2 pxy = (f2){state0[0], state0[1]}; float pz = state0[2];
    f2 vxy = (f2){state0[3], state0[4]}; float vz = state0[5];

    float dotpp = dotP(pxy, pz);
    float dotpv = dotP(vxy, vz);
    float dotvv = dotV(vxy, vz);
    float base0 = b1r + dotpp + dotvv;
    f2 PB2xy = fma2(f2s(hd),  vxy, pxy); float PB2z = fmaf(hd,  vz, pz);
    f2 PB4xy = fma2(f2s(dtf), vxy, pxy); float PB4z = fmaf(dtf, vz, pz);
    float PP2raw = fmaf(hd,  dotpv, base0);
    float PP4raw = fmaf(dtf, dotpv, base0);
    G3 g1 = gravity(pxy, pz);
    f2 gsb1xy = g1.xy + sbxy; float gsb1z = g1.z + sbz;
    float PP2full = fmaf(hd, dotV(gsb1xy, gsb1z), PP2raw);
    float preS1 = base0;

    for (int m = 0; m < M; ++m) {
        float s0, s1, s2;
        // ---------------- STAGE 1 ----------------
        mlpchain(preS1, s0, s1, s2);
        float pre2 = fmaf(wcH2, s2, fmaf(wcH1, s1, fmaf(wcH0, s0, PP2full)));
        f2 a1xy = fma2(f2s(scale), (f2){s0, s1}, gsb1xy);
        float a1z = fmaf(scale, s2, gsb1z);
        G3 g2 = gravity(PB2xy, PB2z);
        f2 gsb2xy = g2.xy + sbxy; float gsb2z = g2.z + sbz;
        f2 p3xy = fma2(f2s(hd2), a1xy, PB2xy); float p3z = fmaf(hd2, a1z, PB2z);
        float PP3full = fmaf(hd2, dotP(a1xy, a1z), PP2raw);
        PP3full = fmaf(hd, dotV(gsb2xy, gsb2z), PP3full);

        // ---------------- STAGE 2 ----------------
        mlpchain(pre2, s0, s1, s2);
        float pre3 = fmaf(wcH2, s2, fmaf(wcH1, s1, fmaf(wcH0, s0, PP3full)));
        f2 a2xy = fma2(f2s(scale), (f2){s0, s1}, gsb2xy);
        float a2z = fmaf(scale, s2, gsb2z);
        G3 g3 = gravity(p3xy, p3z);
        f2 gsb3xy = g3.xy + sbxy; float gsb3z = g3.z + sbz;
        f2 p4xy = fma2(f2s(dthd), a2xy, PB4xy); float p4z = fmaf(dthd, a2z, PB4z);
        float PP4full = fmaf(dthd, dotP(a2xy, a2z), PP4raw);
        PP4full = fmaf(dtf, dotV(gsb3xy, gsb3z), PP4full);
        f2 vkxy = fma2(f2s(2.0f), a2xy, a1xy); float vkz = fmaf(2.0f, a2z, a1z);
        f2 saxy = a1xy + a2xy; float saz = a1z + a2z;

        // ---------------- STAGE 3 ----------------
        mlpchain(pre3, s0, s1, s2);
        float pre4 = fmaf(wcD2, s2, fmaf(wcD1, s1, fmaf(wcD0, s0, PP4full)));
        f2 a3xy = fma2(f2s(scale), (f2){s0, s1}, gsb3xy);
        float a3z = fmaf(scale, s2, gsb3z);
        G3 g4 = gravity(p4xy, p4z);
        f2 gsb4xy = g4.xy + sbxy; float gsb4z = g4.z + sbz;
        saxy = saxy + a3xy; saz = saz + a3z;
        f2 pnxy = fma2(f2s(dt26), saxy, PB4xy); float pnz = fmaf(dt26, saz, PB4z);
        vkxy = fma2(f2s(2.0f), a3xy, vkxy); vkz = fmaf(2.0f, a3z, vkz);
        f2 vpxy = fma2(f2s(dt6), vkxy, vxy); float vpz = fmaf(dt6, vkz, vz);
        float dotppn = dotP(pnxy, pnz);
        float PP1full = b1r + dotppn + dotV(vpxy, vpz);
        PP1full = fmaf(dt6, dotV(gsb4xy, gsb4z), PP1full);

        // ---------------- STAGE 4 ----------------
        mlpchain(pre4, s0, s1, s2);
        preS1 = fmaf(wc62, s2, fmaf(wc61, s1, fmaf(wc60, s0, PP1full)));
        f2 a4xy = fma2(f2s(scale), (f2){s0, s1}, gsb4xy);
        float a4z = fmaf(scale, s2, gsb4z);
        f2 vnxy = fma2(f2s(dt6), a4xy, vpxy); float vnz = fmaf(dt6, a4z, vpz);
        G3 g1n = gravity(pnxy, pnz);
        gsb1xy = g1n.xy + sbxy; gsb1z = g1n.z + sbz;
        PB2xy = fma2(f2s(hd),  vnxy, pnxy); PB2z = fmaf(hd,  vnz, pnz);
        PB4xy = fma2(f2s(dtf), vnxy, pnxy); PB4z = fmaf(dtf, vnz, pnz);
        float dotpv2 = dotP(vnxy, vnz);
        float dotvv2 = dotV(vnxy, vnz);
        float base0n = b1r + dotppn + dotvv2;
        PP2raw = fmaf(hd,  dotpv2, base0n);
        PP4raw = fmaf(dtf, dotpv2, base0n);
        PP2full = fmaf(hd, dotV(gsb1xy, gsb1z), PP2raw);
        vxy = vnxy; vz = vnz;

        if (tid == 0) {
            float2* op = (float2*)(out + (size_t)m * 6);
            op[0] = make_float2(pnxy.x, pnxy.y);
            op[1] = make_float2(pnz, vnxy.x);
            op[2] = make_float2(vnxy.y, vnz);
        }
    }
}

extern "C" void kernel_launch(void* const* d_in, const int* in_sizes, int n_in,
                              void* d_out, int out_size, void* d_ws, size_t ws_size,
                              hipStream_t stream) {
    const float* state0 = (const float*)d_in[0];
    // d_in[1] = eval_times (only its length matters)
    const float* W1 = (const float*)d_in[2];
    const float* b1 = (const float*)d_in[3];
    const float* W2 = (const float*)d_in[4];
    const float* b2 = (const float*)d_in[5];
    const float* W3 = (const float*)d_in[6];
    const float* b3 = (const float*)d_in[7];
    const float* ls = (const float*)d_in[8];
    // d_in[9] = t0 (unused)
    const int* pdt  = (const int*)d_in[10];
    const int M = in_sizes[1];

    node_kernel<<<dim3(1), dim3(64), 0, stream>>>(
        state0, W1, b1, W2, b2, W3, b3, ls, pdt, (float*)d_out, M);
}

// Round 6
// 8713.178 us; speedup vs baseline: 1.5983x; 1.2009x over previous
//
#include <hip/hip_runtime.h>
#include <math.h>

// NeuralODE: sequential RK4 orbit propagation, J2-J5 gravity + tiny MLP.
// Single wave; measured issue model: 1 instr per 4cy cadence -> minimize slots.
// R6: hand-fused DPP asm for L2 (15 ops) and L3 (8 ops, x/y packed via the
// duplicated h2 copies), scale*b3 folded into gravity. ~157 -> ~97 slots/eval.
//
// Lane map: out-neuron o = (tid&15)+16*bit4(tid); input-half ibase = 16*bit5.
//  row0:(o 0-15, ib0) row1:(o16-31, ib0) row2:(o 0-15, ib16) row3:(o16-31, ib16)
//  L1: lane's pre delivered via prefolded bases + 3-fma handoff.
//  L2: 15 v_{mul,fmac}_f32_dpp row_ror:k (weights self-calibrated at init) +
//      1 plain fma; permlane32_swap self-SUM adds the other input half.
//  L3: h2 duplicated across ibase halves -> rows0,1 reduce w3x.h2, rows2,3
//      reduce w3y.h2 (per-lane select), z on all; 8 fused dpp row_ror adds,
//      readlane(0)+(16) / (32)+(48) per dot.

namespace {
constexpr double dMU = 398600.4418;
constexpr double dRE = 6378.137;
constexpr double dJ2 = 0.00108262668;
constexpr double dJ3 = -2.53265648e-06;
constexpr double dJ4 = -1.61962159e-06;
constexpr double dJ5 = -2.27296082e-07;

constexpr float MU_F = (float)dMU;
constexpr float C2_F = (float)(-1.5 * dJ2 * dMU * dRE * dRE);
constexpr float C3_F = (float)(-2.5 * dJ3 * dMU * dRE * dRE * dRE);
constexpr float C4_F = (float)(15.0 / 8.0 * dJ4 * dMU * dRE * dRE * dRE * dRE);
constexpr float C5_F = (float)(3.0 / 8.0 * dJ5 * dMU * dRE * dRE * dRE * dRE * dRE);
constexpr float D5_F = (float)(-(15.0 / 8.0) * dJ5 * dMU * dRE * dRE * dRE * dRE * dRE);
constexpr float IRREF = (float)(1.0 / 7000.0);
constexpr float IVREF = (float)(1.0 / 7.5);
constexpr float AREF  = (float)(7.5 * 7.5 / 7000.0);
constexpr float L2E2  = 2.8853900817779268f;  // 2*log2(e)
} // namespace

typedef float f2 __attribute__((ext_vector_type(2)));
__device__ __forceinline__ f2 f2s(float s) { return (f2){s, s}; }
__device__ __forceinline__ f2 fma2(f2 a, f2 b, f2 c) {
    return __builtin_elementwise_fma(a, b, c);
}

template <int CTRL>
__device__ __forceinline__ int roti(int x) {
    return __builtin_amdgcn_update_dpp(0, x, CTRL, 0xf, 0xf, true);
}
// a+b = x[l] + x[l^32]  (verified R3 primitive; orientation-proof sum)
__device__ __forceinline__ float swap32sum(float x) {
    int a = __float_as_int(x), b = __float_as_int(x);
    asm("s_nop 0\n\tv_permlane32_swap_b32 %0, %1\n\ts_nop 0"
        : "+v"(a), "+v"(b));
    return __int_as_float(a) + __int_as_float(b);
}
__device__ __forceinline__ float rdl(float x, int lane) {
    return __int_as_float(__builtin_amdgcn_readlane(__float_as_int(x), lane));
}
// input already scaled by 2*log2e: tanh = 1 - 2/(2^sp + 1)
__device__ __forceinline__ float tanhx(float sp) {
    float e = __builtin_amdgcn_exp2f(sp);
    return fmaf(-2.0f, __builtin_amdgcn_rcpf(e + 1.0f), 1.0f);
}

struct G3 { f2 xy; float z; };

__global__ void __launch_bounds__(64, 1)
node_kernel(const float* __restrict__ state0,
            const float* __restrict__ W1, const float* __restrict__ b1,
            const float* __restrict__ W2, const float* __restrict__ b2,
            const float* __restrict__ W3, const float* __restrict__ b3,
            const float* __restrict__ plog_scale,
            const int*  __restrict__ pdt,
            float* __restrict__ out, int M)
{
    const int tid  = (int)threadIdx.x;
    const int lid  = tid & 15;
    const int o    = lid + (((tid >> 4) & 1) << 4);  // output neuron
    const int ibase = ((tid >> 5) & 1) << 4;          // input half base
    const int nin  = lid + ibase;                     // input neuron (L1)

    // dt arrives as a 1-element array; sniff int32 vs float32 bit pattern.
    int db = *pdt;
    float dtf = (db >= 1 && db <= 1000000) ? (float)db : __int_as_float(db);
    const float hd   = 0.5f * dtf;
    const float dt6  = dtf * (1.0f / 6.0f);
    const float hd2  = hd * hd;
    const float dthd = dtf * hd;
    const float dt26 = dtf * dtf * (1.0f / 6.0f);

    const float scale =
        __builtin_amdgcn_exp2f(plog_scale[0] * 1.4426950408889634f) * AREF;
    const f2   sbxy = (f2){scale * b3[0], scale * b3[1]};
    const float sbz = scale * b3[2];

    // ---- per-lane weights (pre-scaled by 2*log2e where they feed a tanh) ----
    const float w1p0 = W1[nin * 6 + 0] * (L2E2 * IRREF);
    const float w1p1 = W1[nin * 6 + 1] * (L2E2 * IRREF);
    const float w1p2 = W1[nin * 6 + 2] * (L2E2 * IRREF);
    const float w1v0 = W1[nin * 6 + 3] * (L2E2 * IVREF);
    const float w1v1 = W1[nin * 6 + 4] * (L2E2 * IVREF);
    const float w1v2 = W1[nin * 6 + 5] * (L2E2 * IVREF);
    const float b1r  = b1[nin] * L2E2;

    // self-calibrated DPP rotation source map (within-row lane index)
    int ns1  = roti<0x121>(lid), ns2  = roti<0x122>(lid), ns3  = roti<0x123>(lid);
    int ns4  = roti<0x124>(lid), ns5  = roti<0x125>(lid), ns6  = roti<0x126>(lid);
    int ns7  = roti<0x127>(lid), ns8  = roti<0x128>(lid), ns9  = roti<0x129>(lid);
    int ns10 = roti<0x12A>(lid), ns11 = roti<0x12B>(lid), ns12 = roti<0x12C>(lid);
    int ns13 = roti<0x12D>(lid), ns14 = roti<0x12E>(lid), ns15 = roti<0x12F>(lid);
    const float* W2r = W2 + o * 32 + ibase;
    float w2r[16];
    w2r[0]  = W2r[lid]  * L2E2;
    w2r[1]  = W2r[ns1]  * L2E2;  w2r[2]  = W2r[ns2]  * L2E2;
    w2r[3]  = W2r[ns3]  * L2E2;  w2r[4]  = W2r[ns4]  * L2E2;
    w2r[5]  = W2r[ns5]  * L2E2;  w2r[6]  = W2r[ns6]  * L2E2;
    w2r[7]  = W2r[ns7]  * L2E2;  w2r[8]  = W2r[ns8]  * L2E2;
    w2r[9]  = W2r[ns9]  * L2E2;  w2r[10] = W2r[ns10] * L2E2;
    w2r[11] = W2r[ns11] * L2E2;  w2r[12] = W2r[ns12] * L2E2;
    w2r[13] = W2r[ns13] * L2E2;  w2r[14] = W2r[ns14] * L2E2;
    w2r[15] = W2r[ns15] * L2E2;
    const float b2h = b2[o] * (0.5f * L2E2);  // halved: swap32 sum doubles it
    // L3 packed weights: ibase-0 copy reduces x-dot, ibase-16 copy the y-dot.
    const float w3xy = (ibase == 0) ? W3[o] : W3[32 + o];
    const float w3z  = W3[64 + o];

    // chain-out weight vectors (scale premultiplied)
    const float wcH0 = (scale * hd)  * w1v0, wcH1 = (scale * hd)  * w1v1,
                wcH2 = (scale * hd)  * w1v2;
    const float wcD0 = (scale * dtf) * w1v0, wcD1 = (scale * dtf) * w1v1,
                wcD2 = (scale * dtf) * w1v2;
    const float wc60 = (scale * dt6) * w1v0, wc61 = (scale * dt6) * w1v1,
                wc62 = (scale * dt6) * w1v2;

    auto dotP = [&](f2 xy, float z) {
        return fmaf(w1p2, z, fmaf(w1p1, xy.y, w1p0 * xy.x));
    };
    auto dotV = [&](f2 xy, float z) {
        return fmaf(w1v2, z, fmaf(w1v1, xy.y, w1v0 * xy.x));
    };

    // gravity with scale*b3 folded in: returns g + sb.
    auto gravity = [&](f2 pxy, float pz) -> G3 {
        float zz = pz * pz;
        float r2 = fmaf(pxy.x, pxy.x, fmaf(pxy.y, pxy.y, zz));
        float ir = __builtin_amdgcn_rsqf(r2);
        float ir2 = ir * ir, ir3 = ir2 * ir;
        float s  = zz * ir2;
        float s2 = s * s;
        f2 qp  = fma2(f2s(-5.0f), f2s(s), (f2){1.0f, 3.0f});
        f2 p4p = fma2(f2s(21.0f), f2s(s2),
                      fma2((f2){-14.0f, -70.0f / 3.0f}, f2s(s), (f2){1.0f, 5.0f}));
        f2 p5p = fma2(f2s(231.0f), f2s(s2),
                      fma2((f2){-210.0f, -315.0f}, f2s(s), (f2){35.0f, 105.0f}));
        f2 t3p = fma2(f2s(-7.0f), f2s(s), (f2){3.0f, 6.0f});
        float t3  = pz * t3p.x;
        float p3z = fmaf(s, t3p.y, -0.6f);
        float t5  = pz * p5p.x;
        f2 inner = (f2){fmaf(C3_F, t3, C4_F * p4p.x), C4_F * p4p.y};
        f2 H = fma2(f2s(ir2), (f2){C5_F * t5, 0.0f}, inner);
        H = fma2(f2s(ir2), H, f2s(C2_F) * qp);
        H = fma2(f2s(ir2), H, f2s(-MU_F));
        float Gxy = ir3 * H.x;
        float ir5 = ir3 * ir2;
        float w = fmaf(C5_F, s * p5p.y, D5_F);
        w = fmaf(ir2, w, C3_F * p3z);
        G3 g;
        g.xy = fma2(pxy, f2s(Gxy), sbxy);
        g.z  = fmaf(pz * ir3, H.y, fmaf(ir5, w, sbz));
        return g;
    };

    // MLP chain: pre(scaled) -> uniform (s0,s1,s2) = W3 . tanh(W2 tanh-layer)
    auto mlpchain = [&](float pre, float& s0, float& s1, float& s2) {
        float h1 = tanhx(pre);
        float a0 = fmaf(h1, w2r[0], b2h);
        float a1, a2, a3;
        // 15 DPP-fused MACs; s_nop 1 covers VALU-write(h1) -> DPP-read hazard.
        asm("s_nop 1\n\t"
            "v_mul_f32_dpp %1, %4, %5 row_ror:1 row_mask:0xf bank_mask:0xf\n\t"
            "v_mul_f32_dpp %2, %4, %6 row_ror:2 row_mask:0xf bank_mask:0xf\n\t"
            "v_mul_f32_dpp %3, %4, %7 row_ror:3 row_mask:0xf bank_mask:0xf\n\t"
            "v_fmac_f32_dpp %0, %4, %8 row_ror:4 row_mask:0xf bank_mask:0xf\n\t"
            "v_fmac_f32_dpp %1, %4, %9 row_ror:5 row_mask:0xf bank_mask:0xf\n\t"
            "v_fmac_f32_dpp %2, %4, %10 row_ror:6 row_mask:0xf bank_mask:0xf\n\t"
            "v_fmac_f32_dpp %3, %4, %11 row_ror:7 row_mask:0xf bank_mask:0xf\n\t"
            "v_fmac_f32_dpp %0, %4, %12 row_ror:8 row_mask:0xf bank_mask:0xf\n\t"
            "v_fmac_f32_dpp %1, %4, %13 row_ror:9 row_mask:0xf bank_mask:0xf\n\t"
            "v_fmac_f32_dpp %2, %4, %14 row_ror:10 row_mask:0xf bank_mask:0xf\n\t"
            "v_fmac_f32_dpp %3, %4, %15 row_ror:11 row_mask:0xf bank_mask:0xf\n\t"
            "v_fmac_f32_dpp %0, %4, %16 row_ror:12 row_mask:0xf bank_mask:0xf\n\t"
            "v_fmac_f32_dpp %1, %4, %17 row_ror:13 row_mask:0xf bank_mask:0xf\n\t"
            "v_fmac_f32_dpp %2, %4, %18 row_ror:14 row_mask:0xf bank_mask:0xf\n\t"
            "v_fmac_f32_dpp %3, %4, %19 row_ror:15 row_mask:0xf bank_mask:0xf"
            : "+v"(a0), "=&v"(a1), "=&v"(a2), "=&v"(a3)
            : "v"(h1),
              "v"(w2r[1]), "v"(w2r[2]), "v"(w2r[3]), "v"(w2r[4]),
              "v"(w2r[5]), "v"(w2r[6]), "v"(w2r[7]), "v"(w2r[8]),
              "v"(w2r[9]), "v"(w2r[10]), "v"(w2r[11]), "v"(w2r[12]),
              "v"(w2r[13]), "v"(w2r[14]), "v"(w2r[15]));
        float accA = (a0 + a2) + (a1 + a3);
        float pre2 = swap32sum(accA);       // + other input half (+b2)
        float h2 = tanhx(pre2);
        float r01 = w3xy * h2;              // x-dot on rows0,1; y-dot on rows2,3
        float r2v = w3z * h2;
        // Fused rotate-reduce (direction-independent closure); two interleaved
        // chains hide the DPP read-after-write wait states; trailing s_nop
        // covers the readlane-after-VALU hazard.
        asm("s_nop 1\n\t"
            "v_add_f32_dpp %0, %0, %0 row_ror:1 row_mask:0xf bank_mask:0xf\n\t"
            "v_add_f32_dpp %1, %1, %1 row_ror:1 row_mask:0xf bank_mask:0xf\n\t"
            "v_add_f32_dpp %0, %0, %0 row_ror:2 row_mask:0xf bank_mask:0xf\n\t"
            "v_add_f32_dpp %1, %1, %1 row_ror:2 row_mask:0xf bank_mask:0xf\n\t"
            "v_add_f32_dpp %0, %0, %0 row_ror:4 row_mask:0xf bank_mask:0xf\n\t"
            "v_add_f32_dpp %1, %1, %1 row_ror:4 row_mask:0xf bank_mask:0xf\n\t"
            "v_add_f32_dpp %0, %0, %0 row_ror:8 row_mask:0xf bank_mask:0xf\n\t"
            "v_add_f32_dpp %1, %1, %1 row_ror:8 row_mask:0xf bank_mask:0xf\n\t"
            "s_nop 0"
            : "+v"(r01), "+v"(r2v));
        s0 = rdl(r01, 0)  + rdl(r01, 16);   // sum w3x.h2
        s1 = rdl(r01, 32) + rdl(r01, 48);   // sum w3y.h2
        s2 = rdl(r2v, 0)  + rdl(r2v, 16);   // sum w3z.h2
    };

    // ---- prologue ----
    f2 pxy = (f2){state0[0], state0[1]}; float pz = state0[2];
    f2 vxy = (f2){state0[3], state0[4]}; float vz = state0[5];

    float dotpp = dotP(pxy, pz);
    float dotpv = dotP(vxy, vz);
    float dotvv = dotV(vxy, vz);
    float base0 = b1r + dotpp + dotvv;
    f2 PB2xy = fma2(f2s(hd),  vxy, pxy); float PB2z = fmaf(hd,  vz, pz);
    f2 PB4xy = fma2(f2s(dtf), vxy, pxy); float PB4z = fmaf(dtf, vz, pz);
    float PP2raw = fmaf(hd,  dotpv, base0);
    float PP4raw = fmaf(dtf, dotpv, base0);
    G3 gsb1 = gravity(pxy, pz);
    f2 gsb1xy = gsb1.xy; float gsb1z = gsb1.z;
    float PP2full = fmaf(hd, dotV(gsb1xy, gsb1z), PP2raw);
    float preS1 = base0;

    for (int m = 0; m < M; ++m) {
        float s0, s1, s2;
        // ---------------- STAGE 1 ----------------
        mlpchain(preS1, s0, s1, s2);
        float pre2 = fmaf(wcH2, s2, fmaf(wcH1, s1, fmaf(wcH0, s0, PP2full)));
        f2 a1xy = fma2(f2s(scale), (f2){s0, s1}, gsb1xy);
        float a1z = fmaf(scale, s2, gsb1z);
        G3 g2 = gravity(PB2xy, PB2z);
        f2 p3xy = fma2(f2s(hd2), a1xy, PB2xy); float p3z = fmaf(hd2, a1z, PB2z);
        float PP3full = fmaf(hd2, dotP(a1xy, a1z), PP2raw);
        PP3full = fmaf(hd, dotV(g2.xy, g2.z), PP3full);

        // ---------------- STAGE 2 ----------------
        mlpchain(pre2, s0, s1, s2);
        float pre3 = fmaf(wcH2, s2, fmaf(wcH1, s1, fmaf(wcH0, s0, PP3full)));
        f2 a2xy = fma2(f2s(scale), (f2){s0, s1}, g2.xy);
        float a2z = fmaf(scale, s2, g2.z);
        G3 g3 = gravity(p3xy, p3z);
        f2 p4xy = fma2(f2s(dthd), a2xy, PB4xy); float p4z = fmaf(dthd, a2z, PB4z);
        float PP4full = fmaf(dthd, dotP(a2xy, a2z), PP4raw);
        PP4full = fmaf(dtf, dotV(g3.xy, g3.z), PP4full);
        f2 vkxy = fma2(f2s(2.0f), a2xy, a1xy); float vkz = fmaf(2.0f, a2z, a1z);
        f2 saxy = a1xy + a2xy; float saz = a1z + a2z;

        // ---------------- STAGE 3 ----------------
        mlpchain(pre3, s0, s1, s2);
        float pre4 = fmaf(wcD2, s2, fmaf(wcD1, s1, fmaf(wcD0, s0, PP4full)));
        f2 a3xy = fma2(f2s(scale), (f2){s0, s1}, g3.xy);
        float a3z = fmaf(scale, s2, g3.z);
        G3 g4 = gravity(p4xy, p4z);
        saxy = saxy + a3xy; saz = saz + a3z;
        f2 pnxy = fma2(f2s(dt26), saxy, PB4xy); float pnz = fmaf(dt26, saz, PB4z);
        vkxy = fma2(f2s(2.0f), a3xy, vkxy); vkz = fmaf(2.0f, a3z, vkz);
        f2 vpxy = fma2(f2s(dt6), vkxy, vxy); float vpz = fmaf(dt6, vkz, vz);
        float dotppn = dotP(pnxy, pnz);
        float PP1full = b1r + dotppn + dotV(vpxy, vpz);
        PP1full = fmaf(dt6, dotV(g4.xy, g4.z), PP1full);

        // ---------------- STAGE 4 ----------------
        mlpchain(pre4, s0, s1, s2);
        preS1 = fmaf(wc62, s2, fmaf(wc61, s1, fmaf(wc60, s0, PP1full)));
        f2 a4xy = fma2(f2s(scale), (f2){s0, s1}, g4.xy);
        float a4z = fmaf(scale, s2, g4.z);
        f2 vnxy = fma2(f2s(dt6), a4xy, vpxy); float vnz = fmaf(dt6, a4z, vpz);
        G3 g1n = gravity(pnxy, pnz);
        gsb1xy = g1n.xy; gsb1z = g1n.z;
        PB2xy = fma2(f2s(hd),  vnxy, pnxy); PB2z = fmaf(hd,  vnz, pnz);
        PB4xy = fma2(f2s(dtf), vnxy, pnxy); PB4z = fmaf(dtf, vnz, pnz);
        float dotpv2 = dotP(vnxy, vnz);
        float dotvv2 = dotV(vnxy, vnz);
        float base0n = b1r + dotppn + dotvv2;
        PP2raw = fmaf(hd,  dotpv2, base0n);
        PP4raw = fmaf(dtf, dotpv2, base0n);
        PP2full = fmaf(hd, dotV(gsb1xy, gsb1z), PP2raw);
        vxy = vnxy; vz = vnz;

        if (tid == 0) {
            float2* op = (float2*)(out + (size_t)m * 6);
            op[0] = make_float2(pnxy.x, pnxy.y);
            op[1] = make_float2(pnz, vnxy.x);
            op[2] = make_float2(vnxy.y, vnz);
        }
    }
}

extern "C" void kernel_launch(void* const* d_in, const int* in_sizes, int n_in,
                              void* d_out, int out_size, void* d_ws, size_t ws_size,
                              hipStream_t stream) {
    const float* state0 = (const float*)d_in[0];
    // d_in[1] = eval_times (only its length matters)
    const float* W1 = (const float*)d_in[2];
    const float* b1 = (const float*)d_in[3];
    const float* W2 = (const float*)d_in[4];
    const float* b2 = (const float*)d_in[5];
    const float* W3 = (const float*)d_in[6];
    const float* b3 = (const float*)d_in[7];
    const float* ls = (const float*)d_in[8];
    // d_in[9] = t0 (unused)
    const int* pdt  = (const int*)d_in[10];
    const int M = in_sizes[1];

    node_kernel<<<dim3(1), dim3(64), 0, stream>>>(
        state0, W1, b1, W2, b2, W3, b3, ls, pdt, (float*)d_out, M);
}